// Round 1
// baseline (628.029 us; speedup 1.0000x reference)
//
#include <hip/hip_runtime.h>

#define DEV __device__ __forceinline__

typedef unsigned short u16;
typedef unsigned int   u32;
typedef __attribute__((ext_vector_type(8))) short short8;   // 8 x bf16 (4 VGPRs)
typedef __attribute__((ext_vector_type(4))) float f32x4;

DEV u16 f2bf(float f) {                       // f32 -> bf16 RNE
  u32 u = __builtin_bit_cast(u32, f);
  u = (u + 0x7FFFu + ((u >> 16) & 1u)) >> 16;
  return (u16)u;
}

DEV void gl_lds16(const void* g, void* l) {   // async global->LDS, 16B/lane
  __builtin_amdgcn_global_load_lds((const __attribute__((address_space(1))) void*)g,
                                   (__attribute__((address_space(3))) void*)l, 16, 0, 0);
}

DEV f32x4 mfma_bf16(short8 a, short8 b, f32x4 c) {
  return __builtin_amdgcn_mfma_f32_16x16x32_bf16(a, b, c, 0, 0, 0);
}

// ---------------- f32 -> bf16 cast (vectorized) ----------------
__global__ __launch_bounds__(256) void f32_to_bf16_k(const float* __restrict__ in,
                                                     u16* __restrict__ out, int n4) {
  int stride = gridDim.x * 256;
  for (int i = blockIdx.x * 256 + threadIdx.x; i < n4; i += stride) {
    float4 v = ((const float4*)in)[i];
    u32 lo = (u32)f2bf(v.x) | ((u32)f2bf(v.y) << 16);
    u32 hi = (u32)f2bf(v.z) | ((u32)f2bf(v.w) << 16);
    ((uint2*)out)[i] = make_uint2(lo, hi);
  }
}

// ---------------- transpose + cast: W[K][N] f32 -> WT[Npad][K] bf16 ----------------
__global__ __launch_bounds__(256) void transpose_to_bf16_k(const float* __restrict__ W,
                                                           u16* __restrict__ WT,
                                                           int K, int N) {
  __shared__ u16 T[64][72];                   // +8 pad breaks bank conflicts
  int k0 = blockIdx.x * 64, n0 = blockIdx.y * 64;
  int t = threadIdx.x;
#pragma unroll
  for (int i = 0; i < 4; ++i) {
    int c = t + i * 256;                      // 16B chunk of 4 f32
    int kr = c >> 4, nc = (c & 15) * 4;
    float4 v = make_float4(0.f, 0.f, 0.f, 0.f);
    if (n0 + nc < N) v = *(const float4*)(W + (size_t)(k0 + kr) * N + n0 + nc);
    T[nc + 0][kr] = f2bf(v.x);
    T[nc + 1][kr] = f2bf(v.y);
    T[nc + 2][kr] = f2bf(v.z);
    T[nc + 3][kr] = f2bf(v.w);
  }
  __syncthreads();
#pragma unroll
  for (int i = 0; i < 2; ++i) {
    int c = t + i * 256;                      // 16B chunk of 8 bf16
    int nr = c >> 3, kc = (c & 7) * 8;
    int4 v = *(const int4*)&T[nr][kc];
    *(int4*)(WT + (size_t)(n0 + nr) * K + k0 + kc) = v;
  }
}

// ---------------- bf16 GEMM, C = A * BT^T + bias (m97-style 128x128 tile) ----------------
// A: [M][K] bf16,  BT: [Npad][K] bf16,  C: [M][ldc] f32 (cols >= Nguard dropped)
__global__ __launch_bounds__(256) void gemm_bt_k(const u16* __restrict__ A,
                                                 const u16* __restrict__ BT,
                                                 float* __restrict__ C,
                                                 const float* __restrict__ bias,
                                                 int K, int ldc, int Nguard, int Ntiles) {
  __shared__ u16 As[128 * 32];
  __shared__ u16 Bs[128 * 32];
  int bid = blockIdx.x;
  int m0 = (bid / Ntiles) * 128, n0 = (bid % Ntiles) * 128;
  int t = threadIdx.x, w = t >> 6, l = t & 63;
  int lr = l & 15, lg = l >> 4;
  int wr = w >> 1, wc = w & 1;

  const u16* Ag0 = A  + (size_t)(m0 + (t >> 2)) * K + (t & 3) * 8;
  const u16* Ag1 = Ag0 + (size_t)64 * K;
  const u16* Bg0 = BT + (size_t)(n0 + (t >> 2)) * K + (t & 3) * 8;
  const u16* Bg1 = Bg0 + (size_t)64 * K;
  u16* AsW0 = As + w * 512;  u16* AsW1 = As + 2048 + w * 512;
  u16* BsW0 = Bs + w * 512;  u16* BsW1 = Bs + 2048 + w * 512;

  f32x4 acc[4][4];
#pragma unroll
  for (int i = 0; i < 4; ++i)
#pragma unroll
    for (int j = 0; j < 4; ++j) acc[i][j] = (f32x4){0.f, 0.f, 0.f, 0.f};

  for (int kt = 0; kt < K; kt += 32) {
    gl_lds16(Ag0 + kt, AsW0);
    gl_lds16(Ag1 + kt, AsW1);
    gl_lds16(Bg0 + kt, BsW0);
    gl_lds16(Bg1 + kt, BsW1);
    __syncthreads();
    short8 af[4], bfr[4];
#pragma unroll
    for (int i = 0; i < 4; ++i) af[i]  = *(const short8*)(As + (wr * 64 + i * 16 + lr) * 32 + lg * 8);
#pragma unroll
    for (int j = 0; j < 4; ++j) bfr[j] = *(const short8*)(Bs + (wc * 64 + j * 16 + lr) * 32 + lg * 8);
#pragma unroll
    for (int i = 0; i < 4; ++i)
#pragma unroll
      for (int j = 0; j < 4; ++j)
        acc[i][j] = mfma_bf16(af[i], bfr[j], acc[i][j]);
    __syncthreads();
  }

#pragma unroll
  for (int j = 0; j < 4; ++j) {
    int col = n0 + wc * 64 + j * 16 + lr;
    if (col < Nguard) {
      float bv = bias[col];
#pragma unroll
      for (int i = 0; i < 4; ++i) {
        size_t base = (size_t)(m0 + wr * 64 + i * 16 + lg * 4) * ldc + col;
#pragma unroll
        for (int r = 0; r < 4; ++r)
          C[base + (size_t)r * ldc] = acc[i][j][r] + bv;
      }
    }
  }
}

// ---------------- YaRN RoPE + split + bf16 cast ----------------
// qkv f32 [S][5120] -> qb bf16 [S][64*64] (x 1/sqrt(D)), kb bf16 [S][8*64], vb bf16 [S][8*64]
__global__ __launch_bounds__(256) void rope_k(const float* __restrict__ qkv,
                                              const int* __restrict__ pos_ids,
                                              u16* __restrict__ qb, u16* __restrict__ kb,
                                              u16* __restrict__ vb) {
  int s = blockIdx.x;
  int t = threadIdx.x;
  __shared__ float cs[32], sn[32];
  if (t < 32) {
    int i = t;
    const double PI = 3.14159265358979323846;
    double pf = exp(log(150000.0) * ((double)i / 32.0));
    double extrap = 1.0 / pf;
    double interp = extrap / 32.0;
    double l2b = 2.0 * log(150000.0);
    double low  = floor(64.0 * log(4096.0 / (32.0 * 2.0 * PI)) / l2b);   // = 8
    double high = ceil (64.0 * log(4096.0 / ( 1.0 * 2.0 * PI)) / l2b);   // = 18
    if (low < 0.0) low = 0.0;
    if (high > 63.0) high = 63.0;
    double ramp = ((double)i - low) / fmax(high - low, 0.001);
    ramp = fmin(fmax(ramp, 0.0), 1.0);
    float invf = (float)(interp * ramp + extrap * (1.0 - ramp));
    float fr = (float)pos_ids[s] * invf;
    float mscale = (float)(0.1 * log(32.0) + 1.0);
    cs[i] = cosf(fr) * mscale;
    sn[i] = sinf(fr) * mscale;
  }
  __syncthreads();
  const float* row = qkv + (size_t)s * 5120;
  // q: 64 heads, rotate & scale by D^-1/2
#pragma unroll
  for (int j = 0; j < 8; ++j) {
    int p = t + j * 256;
    int hh = p >> 5, i = p & 31;
    float x1 = row[hh * 64 + i], x2 = row[hh * 64 + i + 32];
    float c = cs[i], sv = sn[i];
    qb[(size_t)s * 4096 + hh * 64 + i]      = f2bf((x1 * c - x2 * sv) * 0.125f);
    qb[(size_t)s * 4096 + hh * 64 + i + 32] = f2bf((x2 * c + x1 * sv) * 0.125f);
  }
  // k: 8 heads
  {
    int kvh = t >> 5, i = t & 31;
    float x1 = row[4096 + kvh * 64 + i], x2 = row[4096 + kvh * 64 + i + 32];
    float c = cs[i], sv = sn[i];
    kb[(size_t)s * 512 + kvh * 64 + i]      = f2bf(x1 * c - x2 * sv);
    kb[(size_t)s * 512 + kvh * 64 + i + 32] = f2bf(x2 * c + x1 * sv);
  }
  // v: plain cast
  vb[(size_t)s * 512 + t * 2]     = f2bf(row[4608 + t * 2]);
  vb[(size_t)s * 512 + t * 2 + 1] = f2bf(row[4608 + t * 2 + 1]);
}

// ---------------- banded attention with sinks ----------------
// grid (32 blocks, 64 heads); 4 waves x 32 q-rows. Window = 128 causal.
__global__ __launch_bounds__(256, 1) void attn_k(const u16* __restrict__ qb,
                                                 const u16* __restrict__ kb,
                                                 const u16* __restrict__ vb,
                                                 const float* __restrict__ sinks,
                                                 u16* __restrict__ attnb) {
  int n = blockIdx.x, h = blockIdx.y;
  int kvh = h >> 3;
  int t = threadIdx.x, w = t >> 6, l = t & 63;
  int lr = l & 15, lg = l >> 4;
  __shared__ u16 Ks[256 * 72];        // K rows padded 64->72 (2-way banks = free)
  __shared__ u16 VT[64 * 264];        // V transposed [d][m], padded 256->264
  __shared__ u16 Ps[4][32 * 136];     // per-wave P chunk [32 q][128 m], padded
  float sink = sinks[h];

  // stage K and V^T (rows m: global position n*128-128+m; m<128 of block 0 is zero)
  for (int c = t; c < 2048; c += 256) {
    int m = c >> 3, j = c & 7;
    int s = n * 128 - 128 + m;
    int4 kvl = make_int4(0, 0, 0, 0), vvl = make_int4(0, 0, 0, 0);
    if (s >= 0) {
      kvl = *(const int4*)(kb + (size_t)s * 512 + kvh * 64 + j * 8);
      vvl = *(const int4*)(vb + (size_t)s * 512 + kvh * 64 + j * 8);
    }
    *(int4*)(Ks + m * 72 + j * 8) = kvl;
    const u16* ve = (const u16*)&vvl;
#pragma unroll
    for (int e = 0; e < 8; ++e) VT[(j * 8 + e) * 264 + m] = ve[e];
  }
  __syncthreads();

  // Q fragments straight from global (read once, reused for all 16 col-tiles)
  short8 aq[2][2];
#pragma unroll
  for (int i = 0; i < 2; ++i)
#pragma unroll
    for (int kk = 0; kk < 2; ++kk)
      aq[i][kk] = *(const short8*)(qb + (size_t)(n * 128 + w * 32 + i * 16 + lr) * 4096
                                      + h * 64 + kk * 32 + lg * 8);

  // scores: S[q][m], q in wave's 32 rows, m in 0..255
  f32x4 p[2][16];
#pragma unroll
  for (int ct = 0; ct < 16; ++ct) {
    short8 b0 = *(const short8*)(Ks + (ct * 16 + lr) * 72 + lg * 8);
    short8 b1 = *(const short8*)(Ks + (ct * 16 + lr) * 72 + 32 + lg * 8);
#pragma unroll
    for (int i = 0; i < 2; ++i) {
      f32x4 z = (f32x4){0.f, 0.f, 0.f, 0.f};
      z = mfma_bf16(aq[i][0], b0, z);
      z = mfma_bf16(aq[i][1], b1, z);
      p[i][ct] = z;
    }
  }

  // mask + softmax (+sink) ; row lives in 16 lanes (lane&15 = m), reduce via shfl_xor
  float invden[2][4];
#pragma unroll
  for (int i = 0; i < 2; ++i) {
#pragma unroll
    for (int r = 0; r < 4; ++r) {
      int q = w * 32 + i * 16 + lg * 4 + r;
      float best = -1e30f;
#pragma unroll
      for (int ct = 0; ct < 16; ++ct) {
        int m = ct * 16 + lr;
        int delta = q + 128 - m;
        bool valid = (delta >= 0) & (delta < 128) & ((n > 0) | (m >= 128));
        float v = valid ? p[i][ct][r] : -1e30f;
        p[i][ct][r] = v;
        best = fmaxf(best, v);
      }
#pragma unroll
      for (int d = 1; d < 16; d <<= 1) best = fmaxf(best, __shfl_xor(best, d, 64));
      best = fmaxf(best, sink);
      float sum = 0.f;
#pragma unroll
      for (int ct = 0; ct < 16; ++ct) {
        float e = expf(p[i][ct][r] - best);
        p[i][ct][r] = e;
        sum += e;
      }
#pragma unroll
      for (int d = 1; d < 16; d <<= 1) sum += __shfl_xor(sum, d, 64);
      sum += expf(sink - best);
      invden[i][r] = 1.0f / sum;
    }
  }

  // PV: out[q][d] = sum_m P[q][m] V[m][d]; P transposed through per-wave LDS in 2 halves
  f32x4 o[2][4];
#pragma unroll
  for (int qt = 0; qt < 2; ++qt)
#pragma unroll
    for (int dt = 0; dt < 4; ++dt) o[qt][dt] = (f32x4){0.f, 0.f, 0.f, 0.f};

  u16* Pw = Ps[w];
#pragma unroll
  for (int half = 0; half < 2; ++half) {
#pragma unroll
    for (int i = 0; i < 2; ++i)
#pragma unroll
      for (int ct = 0; ct < 8; ++ct)
#pragma unroll
        for (int r = 0; r < 4; ++r)
          Pw[(i * 16 + lg * 4 + r) * 136 + ct * 16 + lr] = f2bf(p[i][half * 8 + ct][r]);
    // per-wave LDS ops are in-order; compiler inserts lgkmcnt before mfma use
#pragma unroll
    for (int ks = 0; ks < 4; ++ks) {
      short8 bv[4];
#pragma unroll
      for (int dt = 0; dt < 4; ++dt)
        bv[dt] = *(const short8*)(VT + (dt * 16 + lr) * 264 + half * 128 + ks * 32 + lg * 8);
#pragma unroll
      for (int qt = 0; qt < 2; ++qt) {
        short8 av = *(const short8*)(Pw + (qt * 16 + lr) * 136 + ks * 32 + lg * 8);
#pragma unroll
        for (int dt = 0; dt < 4; ++dt)
          o[qt][dt] = mfma_bf16(av, bv[dt], o[qt][dt]);
      }
    }
  }

  // write attn rows (bf16), divided by denom
#pragma unroll
  for (int qt = 0; qt < 2; ++qt)
#pragma unroll
    for (int dt = 0; dt < 4; ++dt)
#pragma unroll
      for (int r = 0; r < 4; ++r) {
        int row = n * 128 + w * 32 + qt * 16 + lg * 4 + r;
        int col = h * 64 + dt * 16 + lr;
        attnb[(size_t)row * 4096 + col] = f2bf(o[qt][dt][r] * invden[qt][r]);
      }
}

// ---------------- launch ----------------
extern "C" void kernel_launch(void* const* d_in, const int* in_sizes, int n_in,
                              void* d_out, int out_size, void* d_ws, size_t ws_size,
                              hipStream_t stream) {
  const float* hidden = (const float*)d_in[0];
  const int*   pos    = (const int*)d_in[1];
  const float* w_qkv  = (const float*)d_in[2];
  const float* b_qkv  = (const float*)d_in[3];
  const float* w_o    = (const float*)d_in[4];
  const float* b_o    = (const float*)d_in[5];
  const float* sinks  = (const float*)d_in[6];
  float* out = (float*)d_out;
  char* ws = (char*)d_ws;

  // workspace layout (bytes, all 256-aligned); total ~203 MB
  u16*  hbf   = (u16*)(ws + 0);              // [4096][2880] bf16  (23.6 MB)
  u16*  wqkvT = (u16*)(ws + 23592960);       // [5120][2880] bf16  (29.5 MB)
  u16*  attnb = (u16*)(ws + 0);              // [4096][4096] bf16  (reuses hbf+wqkvT region)
  float* qkv  = (float*)(ws + 53084160);     // [4096][5120] f32   (83.9 MB)
  u16*  q_bf  = (u16*)(ws + 136970240);      // [4096][64][64] bf16
  u16*  k_bf  = (u16*)(ws + 170524672);      // [4096][8][64]  bf16
  u16*  v_bf  = (u16*)(ws + 174718976);      // [4096][8][64]  bf16
  u16*  woT   = (u16*)(ws + 178913280);      // [2944][4096] bf16 (padded, rows>=2880 zero)

  f32_to_bf16_k<<<2048, 256, 0, stream>>>(hidden, hbf, 4096 * 2880 / 4);
  transpose_to_bf16_k<<<dim3(2880 / 64, 5120 / 64), 256, 0, stream>>>(w_qkv, wqkvT, 2880, 5120);
  transpose_to_bf16_k<<<dim3(4096 / 64, 2944 / 64), 256, 0, stream>>>(w_o, woT, 4096, 2880);
  // qkv = hidden @ w_qkv + b_qkv   (M=4096, N=5120, K=2880)
  gemm_bt_k<<<32 * 40, 256, 0, stream>>>(hbf, wqkvT, qkv, b_qkv, 2880, 5120, 5120, 40);
  rope_k<<<4096, 256, 0, stream>>>(qkv, pos, q_bf, k_bf, v_bf);
  attn_k<<<dim3(32, 64), 256, 0, stream>>>(q_bf, k_bf, v_bf, sinks, attnb);
  // out = attn @ w_o + b_o         (M=4096, N=2880 (23 tiles padded), K=4096)
  gemm_bt_k<<<32 * 23, 256, 0, stream>>>(attnb, woT, out, b_o, 4096, 2880, 2880, 23);

  (void)in_sizes; (void)n_in; (void)out_size; (void)ws_size;
}